// Round 5
// baseline (220.917 us; speedup 1.0000x reference)
//
#include <hip/hip_runtime.h>
#include <stdint.h>

#define NTREES 8
#define NNODES 5
#define CC 16
#define BB 8
#define HH 224
#define WW 224
#define NEGF (-1e30f)
#define LN2F 0.6931471805599453f

struct Forest { int par[NTREES * NNODES]; };

// ---------------------------------------------------------------------------
// Host-side bit-exact reproduction of np.random.default_rng(0) forest
// (verified absmax 0.0 vs numpy in rounds 1-4 — do not touch).
// ---------------------------------------------------------------------------
namespace nprng {

struct Pcg {
  __uint128_t state, inc;
  int has_uint32;
  uint32_t uinteger;
};

static inline __uint128_t pcg_mult() {
  return (((__uint128_t)0x2360ED051FC65DA4ULL) << 64) | 0x4385DF649FCCF645ULL;
}

static inline void pcg_step(Pcg& s) { s.state = s.state * pcg_mult() + s.inc; }

static inline uint64_t pcg_next64(Pcg& s) {
  pcg_step(s);
  uint64_t xored = (uint64_t)(s.state >> 64) ^ (uint64_t)s.state;
  unsigned rot = (unsigned)(s.state >> 122);
  return (xored >> rot) | (xored << ((64u - rot) & 63u));
}

static inline uint32_t pcg_next32(Pcg& s) {
  if (s.has_uint32) { s.has_uint32 = 0; return s.uinteger; }
  uint64_t n = pcg_next64(s);
  s.has_uint32 = 1;
  s.uinteger = (uint32_t)(n >> 32);
  return (uint32_t)n;
}

static inline uint32_t lemire32(Pcg& s, uint32_t rng) {
  const uint32_t rng_excl = rng + 1u;
  uint64_t m = (uint64_t)pcg_next32(s) * (uint64_t)rng_excl;
  uint32_t leftover = (uint32_t)m;
  if (leftover < rng_excl) {
    const uint32_t threshold = (uint32_t)((0xFFFFFFFFu - rng) % rng_excl);
    while (leftover < threshold) {
      m = (uint64_t)pcg_next32(s) * (uint64_t)rng_excl;
      leftover = (uint32_t)m;
    }
  }
  return (uint32_t)(m >> 32);
}

static void make_forest(Forest& f) {
  const uint32_t INIT_A = 0x43b0d7e5u, MULT_A = 0x931e8875u;
  const uint32_t INIT_B = 0x8b51f9ddu, MULT_B = 0x58f38dedu;
  const uint32_t MIX_L  = 0xca01f9ddu, MIX_R  = 0x4973f715u;
  uint32_t pool[4];
  uint32_t hc = INIT_A;
  auto hashmix = [&](uint32_t v) -> uint32_t {
    v ^= hc; hc *= MULT_A; v *= hc; v ^= v >> 16; return v;
  };
  auto mix = [&](uint32_t x, uint32_t y) -> uint32_t {
    uint32_t r = MIX_L * x - MIX_R * y; r ^= r >> 16; return r;
  };
  pool[0] = hashmix(0u);
  for (int i = 1; i < 4; ++i) pool[i] = hashmix(0u);
  for (int is = 0; is < 4; ++is)
    for (int id = 0; id < 4; ++id)
      if (is != id) pool[id] = mix(pool[id], hashmix(pool[is]));
  uint32_t st32[8];
  uint32_t hb = INIT_B;
  for (int i = 0; i < 8; ++i) {
    uint32_t dv = pool[i & 3];
    dv ^= hb; hb *= MULT_B; dv *= hb; dv ^= dv >> 16;
    st32[i] = dv;
  }
  uint64_t w64[4];
  for (int i = 0; i < 4; ++i)
    w64[i] = (uint64_t)st32[2 * i] | ((uint64_t)st32[2 * i + 1] << 32);

  __uint128_t initstate = (((__uint128_t)w64[0]) << 64) | w64[1];
  __uint128_t initseq   = (((__uint128_t)w64[2]) << 64) | w64[3];
  Pcg s;
  s.state = 0; s.inc = (initseq << 1) | 1;
  pcg_step(s);
  s.state += initstate;
  pcg_step(s);
  s.has_uint32 = 0; s.uinteger = 0;

  for (int t = 0; t < NTREES; ++t) {
    f.par[t * NNODES + 0] = -1;
    for (int i = 1; i < NNODES; ++i) {
      uint32_t rng = (uint32_t)(i - 1);
      f.par[t * NNODES + i] = (rng == 0) ? 0 : (int)lemire32(s, rng);
    }
  }
}

}  // namespace nprng

// ---------------------------------------------------------------------------
// DPP helpers (asm scan verified absmax 0.0 in R4).
// ---------------------------------------------------------------------------
#define NINF_BITS 0xff800000

template <int ctrl, int rm>
__device__ __forceinline__ float dpp_ninf(float x) {
  int r = __builtin_amdgcn_update_dpp(
      (int)NINF_BITS, __builtin_bit_cast(int, x), ctrl, rm, 0xf, false);
  return __builtin_bit_cast(float, r);
}

__device__ __forceinline__ float wshr1(float t) {
  return dpp_ninf<0x138, 0xf>(t);  // wave_shr:1
}

#define SCAN_SHR(q, N) \
  asm volatile("v_max_f32_dpp %0, %0, %0 row_shr:" #N \
               " row_mask:0xf bank_mask:0xf" : "+v"(q))
#define SCAN_B15(q) \
  asm volatile("v_max_f32_dpp %0, %0, %0 row_bcast:15" \
               " row_mask:0xa bank_mask:0xf" : "+v"(q))
#define SCAN_B31(q) \
  asm volatile("v_max_f32_dpp %0, %0, %0 row_bcast:31" \
               " row_mask:0xc bank_mask:0xf" : "+v"(q))
#define DPP_FENCE(a, b, c, d) \
  asm volatile("s_nop 1" : "+v"(a), "+v"(b), "+v"(c), "+v"(d))

#define ADD4(d, s) { (d).x += (s).x; (d).y += (s).y; (d).z += (s).z; (d).w += (s).w; }

// ---------------------------------------------------------------------------
// One wave per (tree,b,c). Single kernel: inline log2(1+relu(x)), alphas
// factored out (max-plus translation equivariance), epilogue
// expm1(asum + ln2*m). Blocks 128 apart share an x-plane -> same XCD (L2).
//
// Load pipeline: 4-row batches, 2-buffer ping-pong, issue distance = 1 batch.
// Compute per batch (~1800 cyc) > load latency (~1000 cyc) => the s_waitcnt
// before consuming a batch is fully covered regardless of how conservatively
// the compiler places it (the R2/R4 ~960 cyc/row stall was exposed latency
// from the 1-row-granular rotation).
// ---------------------------------------------------------------------------
__global__ __launch_bounds__(64) void fis_kernel(const float* __restrict__ x,
                                                 const float* __restrict__ alphas,
                                                 float* __restrict__ out,
                                                 Forest f) {
  const int lane = threadIdx.x;
  const int blk  = blockIdx.x;
  const int t    = blk >> 7;
  const int bc   = blk & 127;
  const int c    = bc & (CC - 1);
  const int b    = bc >> 4;

  const float* __restrict__ xp = x + (size_t)bc * (HH * WW);

  float asum = 0.f;
#pragma unroll
  for (int i = 0; i < NNODES; ++i) asum += alphas[(t * NNODES + i) * CC + c];

  const int p2 = f.par[t * NNODES + 2];
  const int p3 = f.par[t * NNODES + 3];
  const int p4 = f.par[t * NNODES + 4];
  // p1 is always 0.

  const int  w0  = lane * 4;
  const bool act = (w0 < WW);
  const float* __restrict__ cp = xp + w0;

  const float4 neg4 = make_float4(NEGF, NEGF, NEGF, NEGF);
  float4 pm1 = neg4, pm2 = neg4, pm3 = neg4, pm4 = neg4, racc = neg4;

  // --- one row of the DP ---
  auto row_step = [&](const float4& xr) {
    float4 xv;
    xv.x = act ? __log2f(1.0f + fmaxf(xr.x, 0.0f)) : NEGF;
    xv.y = act ? __log2f(1.0f + fmaxf(xr.y, 0.0f)) : NEGF;
    xv.z = act ? __log2f(1.0f + fmaxf(xr.z, 0.0f)) : NEGF;
    xv.w = act ? __log2f(1.0f + fmaxf(xr.w, 0.0f)) : NEGF;

    // s_j(w) = M_j(h-1, w-1); -inf enters at col 0 via wshr1.
    float b1 = wshr1(pm1.w), b2 = wshr1(pm2.w), b3 = wshr1(pm3.w), b4 = wshr1(pm4.w);
    float4 s1 = make_float4(b1, pm1.x, pm1.y, pm1.z);
    float4 s2 = make_float4(b2, pm2.x, pm2.y, pm2.z);
    float4 s3 = make_float4(b3, pm3.x, pm3.y, pm3.z);
    float4 s4 = make_float4(b4, pm4.x, pm4.y, pm4.z);

    float4 v0 = xv, v1 = xv, v2 = xv, v3 = xv, v4 = xv;
    (void)v4;

    if      (p4 == 0) ADD4(v0, s4) else if (p4 == 1) ADD4(v1, s4)
    else if (p4 == 2) ADD4(v2, s4) else              ADD4(v3, s4);
    if      (p3 == 0) ADD4(v0, s3) else if (p3 == 1) ADD4(v1, s3)
    else              ADD4(v2, s3);
    if      (p2 == 0) ADD4(v0, s2) else              ADD4(v1, s2);
    ADD4(v0, s1);  // p1 == 0 always

    // Local (within-lane) prefix maxes.
    float l10 = v1.x, l11 = fmaxf(l10, v1.y), l12 = fmaxf(l11, v1.z);
    float l20 = v2.x, l21 = fmaxf(l20, v2.y), l22 = fmaxf(l21, v2.z);
    float l30 = v3.x, l31 = fmaxf(l30, v3.y), l32 = fmaxf(l31, v3.z);
    float l40 = v4.x, l41 = fmaxf(l40, v4.y), l42 = fmaxf(l41, v4.z);
    float q1 = fmaxf(l12, v1.w);
    float q2 = fmaxf(l22, v2.w);
    float q3 = fmaxf(l32, v3.w);
    float q4 = fmaxf(l42, v4.w);

    // Wave-level inclusive max-scan, 6 stages x 4 nodes, stage-major.
    DPP_FENCE(q1, q2, q3, q4);
    SCAN_SHR(q1, 1); SCAN_SHR(q2, 1); SCAN_SHR(q3, 1); SCAN_SHR(q4, 1);
    SCAN_SHR(q1, 2); SCAN_SHR(q2, 2); SCAN_SHR(q3, 2); SCAN_SHR(q4, 2);
    SCAN_SHR(q1, 4); SCAN_SHR(q2, 4); SCAN_SHR(q3, 4); SCAN_SHR(q4, 4);
    SCAN_SHR(q1, 8); SCAN_SHR(q2, 8); SCAN_SHR(q3, 8); SCAN_SHR(q4, 8);
    SCAN_B15(q1);    SCAN_B15(q2);    SCAN_B15(q3);    SCAN_B15(q4);
    SCAN_B31(q1);    SCAN_B31(q2);    SCAN_B31(q3);    SCAN_B31(q4);
    DPP_FENCE(q1, q2, q3, q4);

    float e1 = wshr1(q1), e2 = wshr1(q2), e3 = wshr1(q3), e4 = wshr1(q4);

    pm1.x = fmaxf(fmaxf(e1, l10), pm1.x);
    pm1.y = fmaxf(fmaxf(e1, l11), pm1.y);
    pm1.z = fmaxf(fmaxf(e1, l12), pm1.z);
    pm1.w = fmaxf(q1, pm1.w);
    pm2.x = fmaxf(fmaxf(e2, l20), pm2.x);
    pm2.y = fmaxf(fmaxf(e2, l21), pm2.y);
    pm2.z = fmaxf(fmaxf(e2, l22), pm2.z);
    pm2.w = fmaxf(q2, pm2.w);
    pm3.x = fmaxf(fmaxf(e3, l30), pm3.x);
    pm3.y = fmaxf(fmaxf(e3, l31), pm3.y);
    pm3.z = fmaxf(fmaxf(e3, l32), pm3.z);
    pm3.w = fmaxf(q3, pm3.w);
    pm4.x = fmaxf(fmaxf(e4, l40), pm4.x);
    pm4.y = fmaxf(fmaxf(e4, l41), pm4.y);
    pm4.z = fmaxf(fmaxf(e4, l42), pm4.z);
    pm4.w = fmaxf(q4, pm4.w);

    racc.x = fmaxf(racc.x, v0.x);
    racc.y = fmaxf(racc.y, v0.y);
    racc.z = fmaxf(racc.z, v0.z);
    racc.w = fmaxf(racc.w, v0.w);
  };

  // --- 4-row batched, double-buffered pipeline ---
  float4 A0, A1, A2, A3, B0, B1, B2, B3;
  A0 = act ? *(const float4*)(cp + 0 * WW) : neg4;
  A1 = act ? *(const float4*)(cp + 1 * WW) : neg4;
  A2 = act ? *(const float4*)(cp + 2 * WW) : neg4;
  A3 = act ? *(const float4*)(cp + 3 * WW) : neg4;

#define BATCH(C0, C1, C2, C3, N0, N1, N2, N3, hb)                       \
  {                                                                     \
    const bool pf = act && ((hb) + 8 <= HH);                            \
    const float* lp = cp + (size_t)((hb) + 4) * WW;                     \
    N0 = pf ? *(const float4*)(lp + 0 * WW) : neg4;                     \
    N1 = pf ? *(const float4*)(lp + 1 * WW) : neg4;                     \
    N2 = pf ? *(const float4*)(lp + 2 * WW) : neg4;                     \
    N3 = pf ? *(const float4*)(lp + 3 * WW) : neg4;                     \
    row_step(C0); row_step(C1); row_step(C2); row_step(C3);             \
  }

  for (int h = 0; h < HH; h += 8) {
    BATCH(A0, A1, A2, A3, B0, B1, B2, B3, h);
    BATCH(B0, B1, B2, B3, A0, A1, A2, A3, h + 4);
  }
#undef BATCH

  float m = fmaxf(fmaxf(racc.x, racc.y), fmaxf(racc.z, racc.w));
#pragma unroll
  for (int d = 1; d < 64; d <<= 1) m = fmaxf(m, __shfl_xor(m, d));
  if (lane == 0)
    out[((size_t)b * NTREES + t) * CC + c] = expm1f(fmaf(m, LN2F, asum));
}

extern "C" void kernel_launch(void* const* d_in, const int* in_sizes, int n_in,
                              void* d_out, int out_size, void* d_ws, size_t ws_size,
                              hipStream_t stream) {
  const float* x      = (const float*)d_in[0];
  const float* alphas = (const float*)d_in[1];
  float* out          = (float*)d_out;

  Forest f;
  nprng::make_forest(f);  // deterministic; same every call (graph-capture safe)

  dim3 grid(BB * CC * NTREES);  // 1024 single-wave blocks
  dim3 block(64);
  hipLaunchKernelGGL(fis_kernel, grid, block, 0, stream, x, alphas, out, f);
}

// Round 6
// 160.811 us; speedup vs baseline: 1.3738x; 1.3738x over previous
//
#include <hip/hip_runtime.h>
#include <stdint.h>

#define NTREES 8
#define NNODES 5
#define CC 16
#define BB 8
#define HH 224
#define WW 224

struct Forest { int par[NTREES * NNODES]; };

// ---------------------------------------------------------------------------
// Host-side bit-exact reproduction of np.random.default_rng(0) forest
// (verified absmax 0.0 vs numpy in rounds 1-5 — do not touch).
// ---------------------------------------------------------------------------
namespace nprng {

struct Pcg {
  __uint128_t state, inc;
  int has_uint32;
  uint32_t uinteger;
};

static inline __uint128_t pcg_mult() {
  return (((__uint128_t)0x2360ED051FC65DA4ULL) << 64) | 0x4385DF649FCCF645ULL;
}

static inline void pcg_step(Pcg& s) { s.state = s.state * pcg_mult() + s.inc; }

static inline uint64_t pcg_next64(Pcg& s) {
  pcg_step(s);
  uint64_t xored = (uint64_t)(s.state >> 64) ^ (uint64_t)s.state;
  unsigned rot = (unsigned)(s.state >> 122);
  return (xored >> rot) | (xored << ((64u - rot) & 63u));
}

static inline uint32_t pcg_next32(Pcg& s) {
  if (s.has_uint32) { s.has_uint32 = 0; return s.uinteger; }
  uint64_t n = pcg_next64(s);
  s.has_uint32 = 1;
  s.uinteger = (uint32_t)(n >> 32);
  return (uint32_t)n;
}

static inline uint32_t lemire32(Pcg& s, uint32_t rng) {
  const uint32_t rng_excl = rng + 1u;
  uint64_t m = (uint64_t)pcg_next32(s) * (uint64_t)rng_excl;
  uint32_t leftover = (uint32_t)m;
  if (leftover < rng_excl) {
    const uint32_t threshold = (uint32_t)((0xFFFFFFFFu - rng) % rng_excl);
    while (leftover < threshold) {
      m = (uint64_t)pcg_next32(s) * (uint64_t)rng_excl;
      leftover = (uint32_t)m;
    }
  }
  return (uint32_t)(m >> 32);
}

static void make_forest(Forest& f) {
  const uint32_t INIT_A = 0x43b0d7e5u, MULT_A = 0x931e8875u;
  const uint32_t INIT_B = 0x8b51f9ddu, MULT_B = 0x58f38dedu;
  const uint32_t MIX_L  = 0xca01f9ddu, MIX_R  = 0x4973f715u;
  uint32_t pool[4];
  uint32_t hc = INIT_A;
  auto hashmix = [&](uint32_t v) -> uint32_t {
    v ^= hc; hc *= MULT_A; v *= hc; v ^= v >> 16; return v;
  };
  auto mix = [&](uint32_t x, uint32_t y) -> uint32_t {
    uint32_t r = MIX_L * x - MIX_R * y; r ^= r >> 16; return r;
  };
  pool[0] = hashmix(0u);
  for (int i = 1; i < 4; ++i) pool[i] = hashmix(0u);
  for (int is = 0; is < 4; ++is)
    for (int id = 0; id < 4; ++id)
      if (is != id) pool[id] = mix(pool[id], hashmix(pool[is]));
  uint32_t st32[8];
  uint32_t hb = INIT_B;
  for (int i = 0; i < 8; ++i) {
    uint32_t dv = pool[i & 3];
    dv ^= hb; hb *= MULT_B; dv *= hb; dv ^= dv >> 16;
    st32[i] = dv;
  }
  uint64_t w64[4];
  for (int i = 0; i < 4; ++i)
    w64[i] = (uint64_t)st32[2 * i] | ((uint64_t)st32[2 * i + 1] << 32);

  __uint128_t initstate = (((__uint128_t)w64[0]) << 64) | w64[1];
  __uint128_t initseq   = (((__uint128_t)w64[2]) << 64) | w64[3];
  Pcg s;
  s.state = 0; s.inc = (initseq << 1) | 1;
  pcg_step(s);
  s.state += initstate;
  pcg_step(s);
  s.has_uint32 = 0; s.uinteger = 0;

  for (int t = 0; t < NTREES; ++t) {
    f.par[t * NNODES + 0] = -1;
    for (int i = 1; i < NNODES; ++i) {
      uint32_t rng = (uint32_t)(i - 1);
      f.par[t * NNODES + i] = (rng == 0) ? 0 : (int)lemire32(s, rng);
    }
  }
}

}  // namespace nprng

// ---------------------------------------------------------------------------
// DPP helpers. Product space: max identity is 0.0 (all valid values >= 0).
// In-place v_max_f32_dpp scan steps (asm, verified R4/R5): bound_ctrl off,
// dst==src0 => invalid-source lanes keep old value = inclusive-scan semantics.
// Stage-major order spaces dependent DPPs >=3 insts apart (hazard-safe);
// s_nop fences guard asm/non-asm boundaries.
// ---------------------------------------------------------------------------
template <int ctrl, int rm>
__device__ __forceinline__ float dpp_zero(float x) {
  int r = __builtin_amdgcn_update_dpp(
      0, __builtin_bit_cast(int, x), ctrl, rm, 0xf, false);
  return __builtin_bit_cast(float, r);
}

// Shift whole wave right by 1 lane, 0.0 into lane 0 (border sentinel).
__device__ __forceinline__ float wshr1(float t) {
  return dpp_zero<0x138, 0xf>(t);  // wave_shr:1
}

#define SCAN_SHR(q, N) \
  asm volatile("v_max_f32_dpp %0, %0, %0 row_shr:" #N \
               " row_mask:0xf bank_mask:0xf" : "+v"(q))
#define SCAN_B15(q) \
  asm volatile("v_max_f32_dpp %0, %0, %0 row_bcast:15" \
               " row_mask:0xa bank_mask:0xf" : "+v"(q))
#define SCAN_B31(q) \
  asm volatile("v_max_f32_dpp %0, %0, %0 row_bcast:31" \
               " row_mask:0xc bank_mask:0xf" : "+v"(q))
#define DPP_FENCE(a, b, c, d) \
  asm volatile("s_nop 1" : "+v"(a), "+v"(b), "+v"(c), "+v"(d))

#define MUL4(d, s) { (d).x *= (s).x; (d).y *= (s).y; (d).z *= (s).z; (d).w *= (s).w; }

// ---------------------------------------------------------------------------
// One wave per (tree,b,c). PRODUCT-SPACE DP: exp() is an isomorphism
// (R u {-inf}, +, max) -> ([0,inf), *, max), so run the tree DP on
// f = 1+relu(x) with multiply instead of add and 0.0 as the "impossible"
// sentinel. Zero transcendentals in the loop; epilogue out = exp(asum)*m - 1
// == expm1(asum + log m). Alphas factored out (translation equivariance).
//
// ALL loads are unconditional (row index clamped to 223, tail lanes' column
// base clamped to 220 and their values zeroed in VALU): straight-line loads
// give LLVM exact vmcnt counts -> fine-grained s_waitcnt vmcnt(3) instead of
// the conservative full drain that exposed ~1000 cyc/row in R2-R5.
// Blocks 128 apart share an x-plane -> same XCD (L2 reuse).
// ---------------------------------------------------------------------------
__global__ __launch_bounds__(64) void fis_kernel(const float* __restrict__ x,
                                                 const float* __restrict__ alphas,
                                                 float* __restrict__ out,
                                                 Forest f) {
  const int lane = threadIdx.x;
  const int blk  = blockIdx.x;
  const int t    = blk >> 7;
  const int bc   = blk & 127;
  const int c    = bc & (CC - 1);
  const int b    = bc >> 4;

  const float* __restrict__ xp = x + (size_t)bc * (HH * WW);

  float asum = 0.f;
#pragma unroll
  for (int i = 0; i < NNODES; ++i) asum += alphas[(t * NNODES + i) * CC + c];

  const int p2 = f.par[t * NNODES + 2];
  const int p3 = f.par[t * NNODES + 3];
  const int p4 = f.par[t * NNODES + 4];
  // p1 is always 0.

  const int   w0   = lane * 4;
  const bool  act  = (w0 < WW);
  const float mask = act ? 1.0f : 0.0f;             // zero tail lanes' values
  const float* __restrict__ cp = xp + (act ? w0 : (WW - 4));  // clamped, in-bounds

  const float4 zero4 = make_float4(0.f, 0.f, 0.f, 0.f);
  float4 pm1 = zero4, pm2 = zero4, pm3 = zero4, pm4 = zero4, racc = zero4;

  // --- one row of the DP (product space) ---
  auto row_step = [&](const float4& xr) {
    float4 fv;  // f = (1+relu(x)) * lane-mask
    fv.x = (fmaxf(xr.x, 0.0f) + 1.0f) * mask;
    fv.y = (fmaxf(xr.y, 0.0f) + 1.0f) * mask;
    fv.z = (fmaxf(xr.z, 0.0f) + 1.0f) * mask;
    fv.w = (fmaxf(xr.w, 0.0f) + 1.0f) * mask;

    // s_j(w) = M_j(h-1, w-1); 0.0 enters at col 0 via wshr1 (border).
    float b1 = wshr1(pm1.w), b2 = wshr1(pm2.w), b3 = wshr1(pm3.w), b4 = wshr1(pm4.w);
    float4 s1 = make_float4(b1, pm1.x, pm1.y, pm1.z);
    float4 s2 = make_float4(b2, pm2.x, pm2.y, pm2.z);
    float4 s3 = make_float4(b3, pm3.x, pm3.y, pm3.z);
    float4 s4 = make_float4(b4, pm4.x, pm4.y, pm4.z);

    float4 v0 = fv, v1 = fv, v2 = fv, v3 = fv, v4 = fv;
    (void)v4;

    // children subtree products multiply into parents
    if      (p4 == 0) MUL4(v0, s4) else if (p4 == 1) MUL4(v1, s4)
    else if (p4 == 2) MUL4(v2, s4) else              MUL4(v3, s4);
    if      (p3 == 0) MUL4(v0, s3) else if (p3 == 1) MUL4(v1, s3)
    else              MUL4(v2, s3);
    if      (p2 == 0) MUL4(v0, s2) else              MUL4(v1, s2);
    MUL4(v0, s1);  // p1 == 0 always

    // Local (within-lane) prefix maxes.
    float l10 = v1.x, l11 = fmaxf(l10, v1.y), l12 = fmaxf(l11, v1.z);
    float l20 = v2.x, l21 = fmaxf(l20, v2.y), l22 = fmaxf(l21, v2.z);
    float l30 = v3.x, l31 = fmaxf(l30, v3.y), l32 = fmaxf(l31, v3.z);
    float l40 = v4.x, l41 = fmaxf(l40, v4.y), l42 = fmaxf(l41, v4.z);
    float q1 = fmaxf(l12, v1.w);
    float q2 = fmaxf(l22, v2.w);
    float q3 = fmaxf(l32, v3.w);
    float q4 = fmaxf(l42, v4.w);

    // Wave-level inclusive max-scan, 6 stages x 4 nodes, stage-major.
    DPP_FENCE(q1, q2, q3, q4);
    SCAN_SHR(q1, 1); SCAN_SHR(q2, 1); SCAN_SHR(q3, 1); SCAN_SHR(q4, 1);
    SCAN_SHR(q1, 2); SCAN_SHR(q2, 2); SCAN_SHR(q3, 2); SCAN_SHR(q4, 2);
    SCAN_SHR(q1, 4); SCAN_SHR(q2, 4); SCAN_SHR(q3, 4); SCAN_SHR(q4, 4);
    SCAN_SHR(q1, 8); SCAN_SHR(q2, 8); SCAN_SHR(q3, 8); SCAN_SHR(q4, 8);
    SCAN_B15(q1);    SCAN_B15(q2);    SCAN_B15(q3);    SCAN_B15(q4);
    SCAN_B31(q1);    SCAN_B31(q2);    SCAN_B31(q3);    SCAN_B31(q4);
    DPP_FENCE(q1, q2, q3, q4);

    float e1 = wshr1(q1), e2 = wshr1(q2), e3 = wshr1(q3), e4 = wshr1(q4);

    pm1.x = fmaxf(fmaxf(e1, l10), pm1.x);
    pm1.y = fmaxf(fmaxf(e1, l11), pm1.y);
    pm1.z = fmaxf(fmaxf(e1, l12), pm1.z);
    pm1.w = fmaxf(q1, pm1.w);
    pm2.x = fmaxf(fmaxf(e2, l20), pm2.x);
    pm2.y = fmaxf(fmaxf(e2, l21), pm2.y);
    pm2.z = fmaxf(fmaxf(e2, l22), pm2.z);
    pm2.w = fmaxf(q2, pm2.w);
    pm3.x = fmaxf(fmaxf(e3, l30), pm3.x);
    pm3.y = fmaxf(fmaxf(e3, l31), pm3.y);
    pm3.z = fmaxf(fmaxf(e3, l32), pm3.z);
    pm3.w = fmaxf(q3, pm3.w);
    pm4.x = fmaxf(fmaxf(e4, l40), pm4.x);
    pm4.y = fmaxf(fmaxf(e4, l41), pm4.y);
    pm4.z = fmaxf(fmaxf(e4, l42), pm4.z);
    pm4.w = fmaxf(q4, pm4.w);

    racc.x = fmaxf(racc.x, v0.x);
    racc.y = fmaxf(racc.y, v0.y);
    racc.z = fmaxf(racc.z, v0.z);
    racc.w = fmaxf(racc.w, v0.w);
  };

  // --- depth-4 register pipeline, ALL loads unconditional ---
  float4 R0 = *(const float4*)(cp + 0 * WW);
  float4 R1 = *(const float4*)(cp + 1 * WW);
  float4 R2 = *(const float4*)(cp + 2 * WW);
  float4 R3 = *(const float4*)(cp + 3 * WW);

  for (int h = 0; h < HH; h += 4) {
    // clamped prefetch rows (redundant tail loads of row 223 are harmless)
    const int n0 = (h + 4 < HH) ? h + 4 : HH - 1;
    const int n1 = (h + 5 < HH) ? h + 5 : HH - 1;
    const int n2 = (h + 6 < HH) ? h + 6 : HH - 1;
    const int n3 = (h + 7 < HH) ? h + 7 : HH - 1;
    float4 T0 = *(const float4*)(cp + (size_t)n0 * WW);
    float4 T1 = *(const float4*)(cp + (size_t)n1 * WW);
    float4 T2 = *(const float4*)(cp + (size_t)n2 * WW);
    float4 T3 = *(const float4*)(cp + (size_t)n3 * WW);
    row_step(R0);
    row_step(R1);
    row_step(R2);
    row_step(R3);
    R0 = T0; R1 = T1; R2 = T2; R3 = T3;
  }

  float m = fmaxf(fmaxf(racc.x, racc.y), fmaxf(racc.z, racc.w));
#pragma unroll
  for (int d = 1; d < 64; d <<= 1) m = fmaxf(m, __shfl_xor(m, d));
  if (lane == 0)
    out[((size_t)b * NTREES + t) * CC + c] = expf(asum) * m - 1.0f;
}

extern "C" void kernel_launch(void* const* d_in, const int* in_sizes, int n_in,
                              void* d_out, int out_size, void* d_ws, size_t ws_size,
                              hipStream_t stream) {
  const float* x      = (const float*)d_in[0];
  const float* alphas = (const float*)d_in[1];
  float* out          = (float*)d_out;

  Forest f;
  nprng::make_forest(f);  // deterministic; same every call (graph-capture safe)

  dim3 grid(BB * CC * NTREES);  // 1024 single-wave blocks
  dim3 block(64);
  hipLaunchKernelGGL(fis_kernel, grid, block, 0, stream, x, alphas, out, f);
}

// Round 7
// 158.836 us; speedup vs baseline: 1.3908x; 1.0124x over previous
//
#include <hip/hip_runtime.h>
#include <stdint.h>

#define NTREES 8
#define NNODES 5
#define CC 16
#define BB 8
#define HH 224
#define WW 224

struct Forest { int par[NTREES * NNODES]; };

// ---------------------------------------------------------------------------
// Host-side bit-exact reproduction of np.random.default_rng(0) forest
// (verified absmax 0.0 vs numpy in rounds 1-6 — do not touch).
// ---------------------------------------------------------------------------
namespace nprng {

struct Pcg {
  __uint128_t state, inc;
  int has_uint32;
  uint32_t uinteger;
};

static inline __uint128_t pcg_mult() {
  return (((__uint128_t)0x2360ED051FC65DA4ULL) << 64) | 0x4385DF649FCCF645ULL;
}

static inline void pcg_step(Pcg& s) { s.state = s.state * pcg_mult() + s.inc; }

static inline uint64_t pcg_next64(Pcg& s) {
  pcg_step(s);
  uint64_t xored = (uint64_t)(s.state >> 64) ^ (uint64_t)s.state;
  unsigned rot = (unsigned)(s.state >> 122);
  return (xored >> rot) | (xored << ((64u - rot) & 63u));
}

static inline uint32_t pcg_next32(Pcg& s) {
  if (s.has_uint32) { s.has_uint32 = 0; return s.uinteger; }
  uint64_t n = pcg_next64(s);
  s.has_uint32 = 1;
  s.uinteger = (uint32_t)(n >> 32);
  return (uint32_t)n;
}

static inline uint32_t lemire32(Pcg& s, uint32_t rng) {
  const uint32_t rng_excl = rng + 1u;
  uint64_t m = (uint64_t)pcg_next32(s) * (uint64_t)rng_excl;
  uint32_t leftover = (uint32_t)m;
  if (leftover < rng_excl) {
    const uint32_t threshold = (uint32_t)((0xFFFFFFFFu - rng) % rng_excl);
    while (leftover < threshold) {
      m = (uint64_t)pcg_next32(s) * (uint64_t)rng_excl;
      leftover = (uint32_t)m;
    }
  }
  return (uint32_t)(m >> 32);
}

static void make_forest(Forest& f) {
  const uint32_t INIT_A = 0x43b0d7e5u, MULT_A = 0x931e8875u;
  const uint32_t INIT_B = 0x8b51f9ddu, MULT_B = 0x58f38dedu;
  const uint32_t MIX_L  = 0xca01f9ddu, MIX_R  = 0x4973f715u;
  uint32_t pool[4];
  uint32_t hc = INIT_A;
  auto hashmix = [&](uint32_t v) -> uint32_t {
    v ^= hc; hc *= MULT_A; v *= hc; v ^= v >> 16; return v;
  };
  auto mix = [&](uint32_t x, uint32_t y) -> uint32_t {
    uint32_t r = MIX_L * x - MIX_R * y; r ^= r >> 16; return r;
  };
  pool[0] = hashmix(0u);
  for (int i = 1; i < 4; ++i) pool[i] = hashmix(0u);
  for (int is = 0; is < 4; ++is)
    for (int id = 0; id < 4; ++id)
      if (is != id) pool[id] = mix(pool[id], hashmix(pool[is]));
  uint32_t st32[8];
  uint32_t hb = INIT_B;
  for (int i = 0; i < 8; ++i) {
    uint32_t dv = pool[i & 3];
    dv ^= hb; hb *= MULT_B; dv *= hb; dv ^= dv >> 16;
    st32[i] = dv;
  }
  uint64_t w64[4];
  for (int i = 0; i < 4; ++i)
    w64[i] = (uint64_t)st32[2 * i] | ((uint64_t)st32[2 * i + 1] << 32);

  __uint128_t initstate = (((__uint128_t)w64[0]) << 64) | w64[1];
  __uint128_t initseq   = (((__uint128_t)w64[2]) << 64) | w64[3];
  Pcg s;
  s.state = 0; s.inc = (initseq << 1) | 1;
  pcg_step(s);
  s.state += initstate;
  pcg_step(s);
  s.has_uint32 = 0; s.uinteger = 0;

  for (int t = 0; t < NTREES; ++t) {
    f.par[t * NNODES + 0] = -1;
    for (int i = 1; i < NNODES; ++i) {
      uint32_t rng = (uint32_t)(i - 1);
      f.par[t * NNODES + i] = (rng == 0) ? 0 : (int)lemire32(s, rng);
    }
  }
}

}  // namespace nprng

// ---------------------------------------------------------------------------
// DPP helpers. Product space: max identity is 0.0 (all valid values >= 0).
// In-place v_max_f32_dpp scan steps (asm, verified R4-R6): bound_ctrl off,
// dst==src0 => invalid-source lanes keep old value = inclusive-scan semantics.
// Stage-major order spaces dependent DPPs >=3 insts apart (hazard-safe);
// s_nop fences guard asm/non-asm boundaries.
// ---------------------------------------------------------------------------
template <int ctrl, int rm>
__device__ __forceinline__ float dpp_zero(float x) {
  int r = __builtin_amdgcn_update_dpp(
      0, __builtin_bit_cast(int, x), ctrl, rm, 0xf, false);
  return __builtin_bit_cast(float, r);
}

// Shift whole wave right by 1 lane, 0.0 into lane 0 (border sentinel).
__device__ __forceinline__ float wshr1(float t) {
  return dpp_zero<0x138, 0xf>(t);  // wave_shr:1
}

#define SCAN_SHR(q, N) \
  asm volatile("v_max_f32_dpp %0, %0, %0 row_shr:" #N \
               " row_mask:0xf bank_mask:0xf" : "+v"(q))
#define SCAN_B15(q) \
  asm volatile("v_max_f32_dpp %0, %0, %0 row_bcast:15" \
               " row_mask:0xa bank_mask:0xf" : "+v"(q))
#define SCAN_B31(q) \
  asm volatile("v_max_f32_dpp %0, %0, %0 row_bcast:31" \
               " row_mask:0xc bank_mask:0xf" : "+v"(q))
#define DPP_FENCE(a, b, c, d) \
  asm volatile("s_nop 1" : "+v"(a), "+v"(b), "+v"(c), "+v"(d))

#define MUL4(d, s) { (d).x *= (s).x; (d).y *= (s).y; (d).z *= (s).z; (d).w *= (s).w; }

// ---------------------------------------------------------------------------
// One wave per (tree,b,c). PRODUCT-SPACE DP (exp isomorphism of max-plus):
// f = 1+relu(x), children multiply into parents, sentinel 0.0, epilogue
// out = exp(asum)*m - 1. Alphas factored out (translation equivariance).
//
// Tail lanes (cols 224..255) read clamped duplicates of cols 220..223 with
// NO masking: appended duplicate columns are exact no-ops for prefix-max
// (they sit to the right of all real columns) and for the final plane max
// (duplicates of real values). All loads unconditional & in-bounds.
//
// Load pipeline depth EIGHT rows (A=current batch, B=next, T=loading):
// even if LLVM interleaves per-row waits, each consumed row is >=8 rows
// (~2000 cyc) old -> L2/L3/HBM latency fully covered. This attacks the
// ~900 cyc/row idle measured in R6 (one exposed load latency per row).
// Blocks 128 apart share an x-plane -> same XCD (L2 reuse).
// ---------------------------------------------------------------------------
__global__ __launch_bounds__(64) void fis_kernel(const float* __restrict__ x,
                                                 const float* __restrict__ alphas,
                                                 float* __restrict__ out,
                                                 Forest f) {
  const int lane = threadIdx.x;
  const int blk  = blockIdx.x;
  const int t    = blk >> 7;
  const int bc   = blk & 127;
  const int c    = bc & (CC - 1);
  const int b    = bc >> 4;

  const float* __restrict__ xp = x + (size_t)bc * (HH * WW);

  float asum = 0.f;
#pragma unroll
  for (int i = 0; i < NNODES; ++i) asum += alphas[(t * NNODES + i) * CC + c];

  const int p2 = f.par[t * NNODES + 2];
  const int p3 = f.par[t * NNODES + 3];
  const int p4 = f.par[t * NNODES + 4];
  // p1 is always 0.

  const int w0 = lane * 4;
  // Clamped column base: tail lanes duplicate cols 220..223 (exact no-op).
  const float* __restrict__ cp = xp + ((w0 < WW) ? w0 : (WW - 4));

  const float4 zero4 = make_float4(0.f, 0.f, 0.f, 0.f);
  float4 pm1 = zero4, pm2 = zero4, pm3 = zero4, pm4 = zero4, racc = zero4;

  // --- one row of the DP (product space) ---
  auto row_step = [&](const float4& xr) {
    float4 fv;  // f = 1 + relu(x)
    fv.x = fmaxf(xr.x, 0.0f) + 1.0f;
    fv.y = fmaxf(xr.y, 0.0f) + 1.0f;
    fv.z = fmaxf(xr.z, 0.0f) + 1.0f;
    fv.w = fmaxf(xr.w, 0.0f) + 1.0f;

    // s_j(w) = M_j(h-1, w-1); 0.0 enters at col 0 via wshr1 (border).
    float b1 = wshr1(pm1.w), b2 = wshr1(pm2.w), b3 = wshr1(pm3.w), b4 = wshr1(pm4.w);
    float4 s1 = make_float4(b1, pm1.x, pm1.y, pm1.z);
    float4 s2 = make_float4(b2, pm2.x, pm2.y, pm2.z);
    float4 s3 = make_float4(b3, pm3.x, pm3.y, pm3.z);
    float4 s4 = make_float4(b4, pm4.x, pm4.y, pm4.z);

    float4 v0 = fv, v1 = fv, v2 = fv, v3 = fv, v4 = fv;
    (void)v4;

    // children subtree products multiply into parents
    if      (p4 == 0) MUL4(v0, s4) else if (p4 == 1) MUL4(v1, s4)
    else if (p4 == 2) MUL4(v2, s4) else              MUL4(v3, s4);
    if      (p3 == 0) MUL4(v0, s3) else if (p3 == 1) MUL4(v1, s3)
    else              MUL4(v2, s3);
    if      (p2 == 0) MUL4(v0, s2) else              MUL4(v1, s2);
    MUL4(v0, s1);  // p1 == 0 always

    // Local (within-lane) prefix maxes.
    float l10 = v1.x, l11 = fmaxf(l10, v1.y), l12 = fmaxf(l11, v1.z);
    float l20 = v2.x, l21 = fmaxf(l20, v2.y), l22 = fmaxf(l21, v2.z);
    float l30 = v3.x, l31 = fmaxf(l30, v3.y), l32 = fmaxf(l31, v3.z);
    float l40 = v4.x, l41 = fmaxf(l40, v4.y), l42 = fmaxf(l41, v4.z);
    float q1 = fmaxf(l12, v1.w);
    float q2 = fmaxf(l22, v2.w);
    float q3 = fmaxf(l32, v3.w);
    float q4 = fmaxf(l42, v4.w);

    // Wave-level inclusive max-scan, 6 stages x 4 nodes, stage-major.
    DPP_FENCE(q1, q2, q3, q4);
    SCAN_SHR(q1, 1); SCAN_SHR(q2, 1); SCAN_SHR(q3, 1); SCAN_SHR(q4, 1);
    SCAN_SHR(q1, 2); SCAN_SHR(q2, 2); SCAN_SHR(q3, 2); SCAN_SHR(q4, 2);
    SCAN_SHR(q1, 4); SCAN_SHR(q2, 4); SCAN_SHR(q3, 4); SCAN_SHR(q4, 4);
    SCAN_SHR(q1, 8); SCAN_SHR(q2, 8); SCAN_SHR(q3, 8); SCAN_SHR(q4, 8);
    SCAN_B15(q1);    SCAN_B15(q2);    SCAN_B15(q3);    SCAN_B15(q4);
    SCAN_B31(q1);    SCAN_B31(q2);    SCAN_B31(q3);    SCAN_B31(q4);
    DPP_FENCE(q1, q2, q3, q4);

    float e1 = wshr1(q1), e2 = wshr1(q2), e3 = wshr1(q3), e4 = wshr1(q4);

    pm1.x = fmaxf(fmaxf(e1, l10), pm1.x);
    pm1.y = fmaxf(fmaxf(e1, l11), pm1.y);
    pm1.z = fmaxf(fmaxf(e1, l12), pm1.z);
    pm1.w = fmaxf(q1, pm1.w);
    pm2.x = fmaxf(fmaxf(e2, l20), pm2.x);
    pm2.y = fmaxf(fmaxf(e2, l21), pm2.y);
    pm2.z = fmaxf(fmaxf(e2, l22), pm2.z);
    pm2.w = fmaxf(q2, pm2.w);
    pm3.x = fmaxf(fmaxf(e3, l30), pm3.x);
    pm3.y = fmaxf(fmaxf(e3, l31), pm3.y);
    pm3.z = fmaxf(fmaxf(e3, l32), pm3.z);
    pm3.w = fmaxf(q3, pm3.w);
    pm4.x = fmaxf(fmaxf(e4, l40), pm4.x);
    pm4.y = fmaxf(fmaxf(e4, l41), pm4.y);
    pm4.z = fmaxf(fmaxf(e4, l42), pm4.z);
    pm4.w = fmaxf(q4, pm4.w);

    racc.x = fmaxf(racc.x, v0.x);
    racc.y = fmaxf(racc.y, v0.y);
    racc.z = fmaxf(racc.z, v0.z);
    racc.w = fmaxf(racc.w, v0.w);
  };

  // --- depth-8 register pipeline: A = rows h..h+3, B = rows h+4..h+7 ---
  float4 A0 = *(const float4*)(cp + 0 * WW);
  float4 A1 = *(const float4*)(cp + 1 * WW);
  float4 A2 = *(const float4*)(cp + 2 * WW);
  float4 A3 = *(const float4*)(cp + 3 * WW);
  float4 B0 = *(const float4*)(cp + 4 * WW);
  float4 B1 = *(const float4*)(cp + 5 * WW);
  float4 B2 = *(const float4*)(cp + 6 * WW);
  float4 B3 = *(const float4*)(cp + 7 * WW);

#pragma unroll 2
  for (int h = 0; h < HH; h += 4) {
    // Loads for rows h+8..h+11, clamped (tail duplicates of row 223 harmless).
    const int n0 = (h +  8 < HH) ? h +  8 : HH - 1;
    const int n1 = (h +  9 < HH) ? h +  9 : HH - 1;
    const int n2 = (h + 10 < HH) ? h + 10 : HH - 1;
    const int n3 = (h + 11 < HH) ? h + 11 : HH - 1;
    float4 T0 = *(const float4*)(cp + (size_t)n0 * WW);
    float4 T1 = *(const float4*)(cp + (size_t)n1 * WW);
    float4 T2 = *(const float4*)(cp + (size_t)n2 * WW);
    float4 T3 = *(const float4*)(cp + (size_t)n3 * WW);

    row_step(A0);
    row_step(A1);
    row_step(A2);
    row_step(A3);

    A0 = B0; A1 = B1; A2 = B2; A3 = B3;
    B0 = T0; B1 = T1; B2 = T2; B3 = T3;
  }

  float m = fmaxf(fmaxf(racc.x, racc.y), fmaxf(racc.z, racc.w));
#pragma unroll
  for (int d = 1; d < 64; d <<= 1) m = fmaxf(m, __shfl_xor(m, d));
  if (lane == 0)
    out[((size_t)b * NTREES + t) * CC + c] = expf(asum) * m - 1.0f;
}

extern "C" void kernel_launch(void* const* d_in, const int* in_sizes, int n_in,
                              void* d_out, int out_size, void* d_ws, size_t ws_size,
                              hipStream_t stream) {
  const float* x      = (const float*)d_in[0];
  const float* alphas = (const float*)d_in[1];
  float* out          = (float*)d_out;

  Forest f;
  nprng::make_forest(f);  // deterministic; same every call (graph-capture safe)

  dim3 grid(BB * CC * NTREES);  // 1024 single-wave blocks
  dim3 block(64);
  hipLaunchKernelGGL(fis_kernel, grid, block, 0, stream, x, alphas, out, f);
}

// Round 8
// 100.204 us; speedup vs baseline: 2.2047x; 1.5851x over previous
//
#include <hip/hip_runtime.h>
#include <stdint.h>

#define NTREES 8
#define NNODES 5
#define CC 16
#define BB 8
#define HH 224
#define WW 224

struct Forest { int par[NTREES * NNODES]; };
struct Cls { int v[NTREES]; };

// ---------------------------------------------------------------------------
// Host-side bit-exact reproduction of np.random.default_rng(0) forest
// (verified absmax 0.0 vs numpy in rounds 1-6 — do not touch).
// ---------------------------------------------------------------------------
namespace nprng {

struct Pcg {
  __uint128_t state, inc;
  int has_uint32;
  uint32_t uinteger;
};

static inline __uint128_t pcg_mult() {
  return (((__uint128_t)0x2360ED051FC65DA4ULL) << 64) | 0x4385DF649FCCF645ULL;
}

static inline void pcg_step(Pcg& s) { s.state = s.state * pcg_mult() + s.inc; }

static inline uint64_t pcg_next64(Pcg& s) {
  pcg_step(s);
  uint64_t xored = (uint64_t)(s.state >> 64) ^ (uint64_t)s.state;
  unsigned rot = (unsigned)(s.state >> 122);
  return (xored >> rot) | (xored << ((64u - rot) & 63u));
}

static inline uint32_t pcg_next32(Pcg& s) {
  if (s.has_uint32) { s.has_uint32 = 0; return s.uinteger; }
  uint64_t n = pcg_next64(s);
  s.has_uint32 = 1;
  s.uinteger = (uint32_t)(n >> 32);
  return (uint32_t)n;
}

static inline uint32_t lemire32(Pcg& s, uint32_t rng) {
  const uint32_t rng_excl = rng + 1u;
  uint64_t m = (uint64_t)pcg_next32(s) * (uint64_t)rng_excl;
  uint32_t leftover = (uint32_t)m;
  if (leftover < rng_excl) {
    const uint32_t threshold = (uint32_t)((0xFFFFFFFFu - rng) % rng_excl);
    while (leftover < threshold) {
      m = (uint64_t)pcg_next32(s) * (uint64_t)rng_excl;
      leftover = (uint32_t)m;
    }
  }
  return (uint32_t)(m >> 32);
}

static void make_forest(Forest& f) {
  const uint32_t INIT_A = 0x43b0d7e5u, MULT_A = 0x931e8875u;
  const uint32_t INIT_B = 0x8b51f9ddu, MULT_B = 0x58f38dedu;
  const uint32_t MIX_L  = 0xca01f9ddu, MIX_R  = 0x4973f715u;
  uint32_t pool[4];
  uint32_t hc = INIT_A;
  auto hashmix = [&](uint32_t v) -> uint32_t {
    v ^= hc; hc *= MULT_A; v *= hc; v ^= v >> 16; return v;
  };
  auto mix = [&](uint32_t x, uint32_t y) -> uint32_t {
    uint32_t r = MIX_L * x - MIX_R * y; r ^= r >> 16; return r;
  };
  pool[0] = hashmix(0u);
  for (int i = 1; i < 4; ++i) pool[i] = hashmix(0u);
  for (int is = 0; is < 4; ++is)
    for (int id = 0; id < 4; ++id)
      if (is != id) pool[id] = mix(pool[id], hashmix(pool[is]));
  uint32_t st32[8];
  uint32_t hb = INIT_B;
  for (int i = 0; i < 8; ++i) {
    uint32_t dv = pool[i & 3];
    dv ^= hb; hb *= MULT_B; dv *= hb; dv ^= dv >> 16;
    st32[i] = dv;
  }
  uint64_t w64[4];
  for (int i = 0; i < 4; ++i)
    w64[i] = (uint64_t)st32[2 * i] | ((uint64_t)st32[2 * i + 1] << 32);

  __uint128_t initstate = (((__uint128_t)w64[0]) << 64) | w64[1];
  __uint128_t initseq   = (((__uint128_t)w64[2]) << 64) | w64[3];
  Pcg s;
  s.state = 0; s.inc = (initseq << 1) | 1;
  pcg_step(s);
  s.state += initstate;
  pcg_step(s);
  s.has_uint32 = 0; s.uinteger = 0;

  for (int t = 0; t < NTREES; ++t) {
    f.par[t * NNODES + 0] = -1;
    for (int i = 1; i < NNODES; ++i) {
      uint32_t rng = (uint32_t)(i - 1);
      f.par[t * NNODES + i] = (rng == 0) ? 0 : (int)lemire32(s, rng);
    }
  }
}

}  // namespace nprng

// ---------------------------------------------------------------------------
// Host: canonical tree-shape classification. With alphas factored out, all
// leaf subtrees carry the identical DP state (v = fv), so they share one
// scan; internal non-root nodes dedup by subtree shape. 9 classes cover all
// 24 possible parent vectors (exhaustively enumerated):
//  c1 {L,L,L,L}        scans=1   root = L^4
//  c2 {I(L),L,L}       scans=2   A=fv*sL;        root = L^2 * A
//  c3 {I(LL),L}        scans=2   A=fv*sL^2;      root = L * A
//  c4 {I(LLL)}         scans=2   A=fv*sL^3;      root = A
//  c5 {I(L),I(L)}      scans=2   A=fv*sL;        root = A^2
//  c6 {I(I(L)),L}      scans=3   A=fv*sL; B=fv*sA;        root = L * B
//  c7 {I(I(L),L)}      scans=3   A=fv*sL; B=fv*sL*sA;     root = B
//  c9 {I(I(LL))}       scans=3   A=fv*sL^2; B=fv*sA;      root = B
//  c8 {I(I(I(L)))}     scans=4   A=fv*sL; B=fv*sA; C=fv*sB; root = C
// ---------------------------------------------------------------------------
static int classify_tree(const int* p) {  // p[0..4], p[0] = -1
  int nch[NNODES] = {0, 0, 0, 0, 0};
  for (int i = 1; i < NNODES; ++i) nch[p[i]]++;
  int internals[3], nI = 0;
  for (int i = 1; i <= 3; ++i) if (nch[i] > 0) internals[nI++] = i;
  if (nI == 0) return 1;
  if (nI == 1) {
    int m = nch[internals[0]];
    return m == 1 ? 2 : (m == 2 ? 3 : 4);
  }
  if (nI == 2) {
    int i = internals[0], j = internals[1];
    if (p[j] == i) {               // chain i <- j
      if (nch[j] == 2) return 9;   // j has two leaf children
      return (nch[i] - 1 == 1) ? 7 : 6;  // i has extra leaf child?
    }
    return 5;                      // two independent single-leaf internals
  }
  return 8;  // nI == 3: only possibility is the full chain
}

// ---------------------------------------------------------------------------
// Class configs: extra states E1..E3 (beyond shared leaf state), each
// v = fv * sL^E?L * s_prev^E?E?; root v0 = fv * sL^RL * sE1^RE1 * ...
// ---------------------------------------------------------------------------
template <int C> struct Cfg;
template <> struct Cfg<1> { static constexpr int NE=0,E1L=0,E2L=0,E2E1=0,RL=4,RE1=0,RE2=0,RE3=0; };
template <> struct Cfg<2> { static constexpr int NE=1,E1L=1,E2L=0,E2E1=0,RL=2,RE1=1,RE2=0,RE3=0; };
template <> struct Cfg<3> { static constexpr int NE=1,E1L=2,E2L=0,E2E1=0,RL=1,RE1=1,RE2=0,RE3=0; };
template <> struct Cfg<4> { static constexpr int NE=1,E1L=3,E2L=0,E2E1=0,RL=0,RE1=1,RE2=0,RE3=0; };
template <> struct Cfg<5> { static constexpr int NE=1,E1L=1,E2L=0,E2E1=0,RL=0,RE1=2,RE2=0,RE3=0; };
template <> struct Cfg<6> { static constexpr int NE=2,E1L=1,E2L=0,E2E1=1,RL=1,RE1=0,RE2=1,RE3=0; };
template <> struct Cfg<7> { static constexpr int NE=2,E1L=1,E2L=1,E2E1=1,RL=0,RE1=0,RE2=1,RE3=0; };
template <> struct Cfg<8> { static constexpr int NE=3,E1L=1,E2L=0,E2E1=1,RL=0,RE1=0,RE2=0,RE3=1; };
template <> struct Cfg<9> { static constexpr int NE=2,E1L=2,E2L=0,E2E1=1,RL=0,RE1=0,RE2=1,RE3=0; };

// ---------------------------------------------------------------------------
// DPP helpers. Product space: max identity 0.0.
// wshr1: bound_ctrl=1 -> single v_mov_b32_dpp wave_shr:1 (invalid lane 0
// gets 0 = border sentinel). Scan steps: in-place v_max_f32_dpp (asm,
// verified R4-R7): bound_ctrl off, dst==src0 -> invalid-source lanes keep
// old value = inclusive-scan semantics. Guards sized to chain count K so
// dependent same-register DPP ops are always >=2 insts apart.
// ---------------------------------------------------------------------------
__device__ __forceinline__ float wshr1(float t) {
  int r = __builtin_amdgcn_update_dpp(
      0, __builtin_bit_cast(int, t), 0x138, 0xf, 0xf, true);
  return __builtin_bit_cast(float, r);
}

#define SCAN_OP(Q, MODS) \
  asm volatile("v_max_f32_dpp %0, %0, %0 " MODS : "+v"(Q))

#define STAGE(MODS)                                         \
  {                                                         \
    SCAN_OP(q[0], MODS);                                    \
    if constexpr (K > 1) SCAN_OP(q[1], MODS);               \
    if constexpr (K > 2) SCAN_OP(q[2], MODS);               \
    if constexpr (K > 3) SCAN_OP(q[3], MODS);               \
    if constexpr (K == 1) asm volatile("s_nop 1");          \
    else if constexpr (K == 2) asm volatile("s_nop 0");     \
  }

#define FENCE_ALL()                                                             \
  {                                                                             \
    if constexpr (K == 1) asm volatile("s_nop 1" : "+v"(q[0]));                 \
    else if constexpr (K == 2)                                                  \
      asm volatile("s_nop 1" : "+v"(q[0]), "+v"(q[1]));                         \
    else if constexpr (K == 3)                                                  \
      asm volatile("s_nop 1" : "+v"(q[0]), "+v"(q[1]), "+v"(q[2]));             \
    else                                                                        \
      asm volatile("s_nop 1" : "+v"(q[0]), "+v"(q[1]), "+v"(q[2]), "+v"(q[3])); \
  }

#define MUL4(d, s) { (d).x *= (s).x; (d).y *= (s).y; (d).z *= (s).z; (d).w *= (s).w; }
#define MAX4(d, s) { (d).x = fmaxf((d).x,(s).x); (d).y = fmaxf((d).y,(s).y); \
                     (d).z = fmaxf((d).z,(s).z); (d).w = fmaxf((d).w,(s).w); }

template <int E>
__device__ __forceinline__ void powmul(float4& v, const float4& s) {
  if constexpr (E == 4) {
    float4 t = s; MUL4(t, t); MUL4(t, t); MUL4(v, t);
  } else {
    if constexpr (E >= 1) MUL4(v, s);
    if constexpr (E >= 2) MUL4(v, s);
    if constexpr (E >= 3) MUL4(v, s);
  }
}

// ---------------------------------------------------------------------------
// Per-class DP body. Product space (exp isomorphism of max-plus): f =
// (1+relu(x))*mask, children multiply into parents, sentinel 0.0; epilogue
// out = exp(asum)*m - 1. mask zeroes tail lanes (restores R6 exactness: the
// unmasked R7 variant inflated phantom columns, absmax 1920).
// Depth-8 register pipeline, all loads unconditional & clamped in-bounds.
// ---------------------------------------------------------------------------
template <int CLS>
__device__ __forceinline__ void run_tree(const float* __restrict__ cp,
                                         float mask, float asum,
                                         float* __restrict__ outp, int lane) {
  using C = Cfg<CLS>;
  constexpr int K = 1 + C::NE;  // scan chains: shared-leaf state + extras

  const float4 zero4 = make_float4(0.f, 0.f, 0.f, 0.f);
  float4 pm[4] = {zero4, zero4, zero4, zero4};
  float4 racc = zero4;

  auto row_step = [&](const float4& xr) {
    float4 fv;  // f = (1+relu(x)) * mask   (fma: zero cost for the mask)
    fv.x = fmaf(fmaxf(xr.x, 0.f), mask, mask);
    fv.y = fmaf(fmaxf(xr.y, 0.f), mask, mask);
    fv.z = fmaf(fmaxf(xr.z, 0.f), mask, mask);
    fv.w = fmaf(fmaxf(xr.w, 0.f), mask, mask);

    // s[k](w) = M_k(h-1, w-1); 0.0 border enters at col 0 via wshr1.
    float4 s[4];
#pragma unroll
    for (int k = 0; k < K; ++k)
      s[k] = make_float4(wshr1(pm[k].w), pm[k].x, pm[k].y, pm[k].z);

    // Root: v0 = fv * sL^RL * sE1^RE1 * sE2^RE2 * sE3^RE3.
    float4 v0 = fv;
    powmul<C::RL>(v0, s[0]);
    if constexpr (C::RE1 > 0) powmul<C::RE1>(v0, s[1]);
    if constexpr (C::RE2 > 0) powmul<C::RE2>(v0, s[2]);
    if constexpr (C::RE3 > 0) powmul<C::RE3>(v0, s[3]);
    MAX4(racc, v0);

    // State values.
    float4 vv[4];
    vv[0] = fv;  // shared leaf state
    if constexpr (C::NE >= 1) { vv[1] = fv; powmul<C::E1L>(vv[1], s[0]); }
    if constexpr (C::NE >= 2) {
      vv[2] = fv; powmul<C::E2L>(vv[2], s[0]); powmul<C::E2E1>(vv[2], s[1]);
    }
    if constexpr (C::NE >= 3) { vv[3] = fv; powmul<1>(vv[3], s[2]); }

    // Local (within-lane) prefix maxes.
    float l0[4], l1[4], l2[4], q[4];
#pragma unroll
    for (int k = 0; k < K; ++k) {
      l0[k] = vv[k].x;
      l1[k] = fmaxf(l0[k], vv[k].y);
      l2[k] = fmaxf(l1[k], vv[k].z);
      q[k]  = fmaxf(l2[k], vv[k].w);
    }

    // Wave-level inclusive max-scan, 6 stages x K chains.
    FENCE_ALL();
    STAGE("row_shr:1 row_mask:0xf bank_mask:0xf");
    STAGE("row_shr:2 row_mask:0xf bank_mask:0xf");
    STAGE("row_shr:4 row_mask:0xf bank_mask:0xf");
    STAGE("row_shr:8 row_mask:0xf bank_mask:0xf");
    STAGE("row_bcast:15 row_mask:0xa bank_mask:0xf");
    STAGE("row_bcast:31 row_mask:0xc bank_mask:0xf");
    FENCE_ALL();

#pragma unroll
    for (int k = 0; k < K; ++k) {
      float e = wshr1(q[k]);
      pm[k].x = fmaxf(fmaxf(e, l0[k]), pm[k].x);
      pm[k].y = fmaxf(fmaxf(e, l1[k]), pm[k].y);
      pm[k].z = fmaxf(fmaxf(e, l2[k]), pm[k].z);
      pm[k].w = fmaxf(q[k], pm[k].w);
    }
  };

  // --- depth-8 register pipeline: A = rows h..h+3, B = rows h+4..h+7 ---
  float4 A0 = *(const float4*)(cp + 0 * WW);
  float4 A1 = *(const float4*)(cp + 1 * WW);
  float4 A2 = *(const float4*)(cp + 2 * WW);
  float4 A3 = *(const float4*)(cp + 3 * WW);
  float4 B0 = *(const float4*)(cp + 4 * WW);
  float4 B1 = *(const float4*)(cp + 5 * WW);
  float4 B2 = *(const float4*)(cp + 6 * WW);
  float4 B3 = *(const float4*)(cp + 7 * WW);

#pragma unroll 2
  for (int h = 0; h < HH; h += 4) {
    const int n0 = (h +  8 < HH) ? h +  8 : HH - 1;
    const int n1 = (h +  9 < HH) ? h +  9 : HH - 1;
    const int n2 = (h + 10 < HH) ? h + 10 : HH - 1;
    const int n3 = (h + 11 < HH) ? h + 11 : HH - 1;
    float4 T0 = *(const float4*)(cp + (size_t)n0 * WW);
    float4 T1 = *(const float4*)(cp + (size_t)n1 * WW);
    float4 T2 = *(const float4*)(cp + (size_t)n2 * WW);
    float4 T3 = *(const float4*)(cp + (size_t)n3 * WW);

    row_step(A0);
    row_step(A1);
    row_step(A2);
    row_step(A3);

    A0 = B0; A1 = B1; A2 = B2; A3 = B3;
    B0 = T0; B1 = T1; B2 = T2; B3 = T3;
  }

  float m = fmaxf(fmaxf(racc.x, racc.y), fmaxf(racc.z, racc.w));
#pragma unroll
  for (int d = 1; d < 64; d <<= 1) m = fmaxf(m, __shfl_xor(m, d));
  if (lane == 0) *outp = expf(asum) * m - 1.0f;
}

// ---------------------------------------------------------------------------
// One wave per (tree,b,c); block-uniform dispatch on the tree's class.
// Blocks 128 apart share an x-plane -> same XCD (L2 reuse).
// ---------------------------------------------------------------------------
__global__ __launch_bounds__(64) void fis_kernel(const float* __restrict__ x,
                                                 const float* __restrict__ alphas,
                                                 float* __restrict__ out,
                                                 Cls cls) {
  const int lane = threadIdx.x;
  const int blk  = blockIdx.x;
  const int t    = blk >> 7;
  const int bc   = blk & 127;
  const int c    = bc & (CC - 1);
  const int b    = bc >> 4;

  const float* __restrict__ xp = x + (size_t)bc * (HH * WW);

  float asum = 0.f;
#pragma unroll
  for (int i = 0; i < NNODES; ++i) asum += alphas[(t * NNODES + i) * CC + c];

  const int   w0   = lane * 4;
  const float mask = (w0 < WW) ? 1.0f : 0.0f;
  const float* __restrict__ cp = xp + ((w0 < WW) ? w0 : (WW - 4));
  float* outp = out + ((size_t)b * NTREES + t) * CC + c;

  switch (cls.v[t]) {
    case 1: run_tree<1>(cp, mask, asum, outp, lane); break;
    case 2: run_tree<2>(cp, mask, asum, outp, lane); break;
    case 3: run_tree<3>(cp, mask, asum, outp, lane); break;
    case 4: run_tree<4>(cp, mask, asum, outp, lane); break;
    case 5: run_tree<5>(cp, mask, asum, outp, lane); break;
    case 6: run_tree<6>(cp, mask, asum, outp, lane); break;
    case 7: run_tree<7>(cp, mask, asum, outp, lane); break;
    case 8: run_tree<8>(cp, mask, asum, outp, lane); break;
    case 9: run_tree<9>(cp, mask, asum, outp, lane); break;
    default: break;
  }
}

extern "C" void kernel_launch(void* const* d_in, const int* in_sizes, int n_in,
                              void* d_out, int out_size, void* d_ws, size_t ws_size,
                              hipStream_t stream) {
  const float* x      = (const float*)d_in[0];
  const float* alphas = (const float*)d_in[1];
  float* out          = (float*)d_out;

  Forest f;
  nprng::make_forest(f);  // deterministic; same every call (graph-capture safe)

  Cls cls;
  for (int t = 0; t < NTREES; ++t)
    cls.v[t] = classify_tree(&f.par[t * NNODES]);

  dim3 grid(BB * CC * NTREES);  // 1024 single-wave blocks
  dim3 block(64);
  hipLaunchKernelGGL(fis_kernel, grid, block, 0, stream, x, alphas, out, cls);
}